// Round 6
// baseline (403.415 us; speedup 1.0000x reference)
//
#include <hip/hip_runtime.h>
#include <math.h>

#define VOCAB 50257
#define EMB   128
#define CTX   200
#define CSLABS 197                 // column slabs of 256
#define RSLABS 4                   // row slabs of 50
#define GRID  (CSLABS * RSLABS)    // 788 blocks = exactly the P1 task count
#define HCHUNKS 32
#define HTASKS (HCHUNKS * EMB)     // 4096
#define NT ((VOCAB + 15) / 16)     // 3142 Ww row-tiles of 16
#define MAGIC 0x5173AB42
#define SPIN_CAP 80000000u

// Barrier state lives in d_ws (poison-filled 0xAA before every timed launch).
// Block 0 zeroes the one-shot counters, then release-stores MAGIC to ready;
// everyone acquire-spins on MAGIC before their first counter use. One-shot
// counters (no reset) make the three barriers race-free within a launch.
__device__ __forceinline__ void gbar(int* ready, int* ctr) {
    __syncthreads();
    if (threadIdx.x == 0) {
        unsigned spin = 0;
        while (__hip_atomic_load(ready, __ATOMIC_ACQUIRE, __HIP_MEMORY_SCOPE_AGENT) != MAGIC
               && ++spin < SPIN_CAP)
            __builtin_amdgcn_s_sleep(8);
        __threadfence();
        __hip_atomic_fetch_add(ctr, 1, __ATOMIC_ACQ_REL, __HIP_MEMORY_SCOPE_AGENT);
        spin = 0;
        while (__hip_atomic_load(ctr, __ATOMIC_ACQUIRE, __HIP_MEMORY_SCOPE_AGENT) < GRID
               && ++spin < SPIN_CAP)
            __builtin_amdgcn_s_sleep(8);
    }
    __syncthreads();
}

__global__ __launch_bounds__(256, 4)
void k_fused(const float* __restrict__ X, const int* __restrict__ lenp,
             const float* __restrict__ Wq, const float* __restrict__ bq,
             const float* __restrict__ Ww, const float* __restrict__ bw,
             float* __restrict__ out,
             float* __restrict__ spart,      // [4][VOCAB]
             float* __restrict__ hpart,      // [32][EMB]
             float* __restrict__ partials,   // [GRID]
             int*   __restrict__ bar) {      // ready@0, c1@16, c2@32, c3@48
    const int b = blockIdx.x, t = threadIdx.x;
    __shared__ float h[EMB];
    __shared__ float wsum[4];
    __shared__ float lzs;
    float* logits = spart;  // alias slab 0: spart last read in P2; logits written in P3

    if (b == 0 && t == 0) {
        __hip_atomic_store(&bar[16], 0, __ATOMIC_RELAXED, __HIP_MEMORY_SCOPE_AGENT);
        __hip_atomic_store(&bar[32], 0, __ATOMIC_RELAXED, __HIP_MEMORY_SCOPE_AGENT);
        __hip_atomic_store(&bar[48], 0, __ATOMIC_RELAXED, __HIP_MEMORY_SCOPE_AGENT);
        __hip_atomic_store(&bar[0], MAGIC, __ATOMIC_RELEASE, __HIP_MEMORY_SCOPE_AGENT);
    }

    // -------- Phase 1: spart[r][v] = sum of 50 rows of X (10-deep MLP) ------
    {
        int c = b % CSLABS, r = b / CSLABS;
        int v = c * 256 + t;
        if (v < VOCAB) {
            const float* p = X + (size_t)(r * 50) * VOCAB + v;
            float a0=0.f,a1=0.f,a2=0.f,a3=0.f,a4=0.f,a5=0.f,a6=0.f,a7=0.f,a8=0.f,a9=0.f;
            for (int i = 0; i < 5; ++i) {
                a0 += p[0 * (size_t)VOCAB];
                a1 += p[1 * (size_t)VOCAB];
                a2 += p[2 * (size_t)VOCAB];
                a3 += p[3 * (size_t)VOCAB];
                a4 += p[4 * (size_t)VOCAB];
                a5 += p[5 * (size_t)VOCAB];
                a6 += p[6 * (size_t)VOCAB];
                a7 += p[7 * (size_t)VOCAB];
                a8 += p[8 * (size_t)VOCAB];
                a9 += p[9 * (size_t)VOCAB];
                p += 10 * (size_t)VOCAB;
            }
            spart[(size_t)(b / CSLABS) * VOCAB + v] =
                (((a0 + a1) + (a2 + a3)) + ((a4 + a5) + (a6 + a7))) + (a8 + a9);
        }
    }
    gbar(bar, bar + 16);

    // -------- Phase 2: hpart[chunk][e] = partial dot(s, Wq[e,:]) ------------
    for (int task = b; task < HTASKS; task += GRID) {
        int chunk = task & (HCHUNKS - 1), e = task >> 5;
        const float* row = Wq + (size_t)e * VOCAB;
        float acc = 0.f;
        for (int v = chunk * 256 + t; v < VOCAB; v += HCHUNKS * 256) {
            float sv = spart[v] + spart[VOCAB + v]
                     + spart[2 * VOCAB + v] + spart[3 * VOCAB + v];
            acc += sv * row[v];
        }
        for (int off = 32; off > 0; off >>= 1) acc += __shfl_down(acc, off, 64);
        int lane = t & 63, wid = t >> 6;
        if (lane == 0) wsum[wid] = acc;
        __syncthreads();
        if (t == 0)
            hpart[chunk * EMB + e] = (wsum[0] + wsum[1]) + (wsum[2] + wsum[3]);
        __syncthreads();   // WAR on wsum before next task
    }
    gbar(bar, bar + 32);

    // -------- Phase 3: logits + per-block exp partial -----------------------
    if (t < EMB) {
        float len = (float)lenp[0];
        float hr = 0.f;
#pragma unroll
        for (int c = 0; c < HCHUNKS; ++c) hr += hpart[c * EMB + t];
        h[t] = (hr + (float)CTX * bq[t]) / len;
    }
    __syncthreads();
    {
        int group = t >> 4;                 // row within 16-row tile
        int c     = t & 15;                 // lane within row
        float eacc = 0.f;
        for (int tile = b; tile < NT; tile += GRID) {
            int v = tile * 16 + group;
            float acc = 0.f;
            if (v < VOCAB) {
                const float4* row = (const float4*)(Ww + (size_t)v * EMB);
                float4 w0 = row[c * 2];
                float4 w1 = row[c * 2 + 1];
                const float* hp = h + c * 8;
                acc = w0.x * hp[0] + w0.y * hp[1] + w0.z * hp[2] + w0.w * hp[3]
                    + w1.x * hp[4] + w1.y * hp[5] + w1.z * hp[6] + w1.w * hp[7];
            }
            acc += __shfl_xor(acc, 1, 64);
            acc += __shfl_xor(acc, 2, 64);
            acc += __shfl_xor(acc, 4, 64);
            acc += __shfl_xor(acc, 8, 64);
            if (v < VOCAB && c == 0) {
                float lg = acc + bw[v];
                logits[v] = lg;
                eacc += expf(lg);
            }
        }
        for (int off = 32; off > 0; off >>= 1) eacc += __shfl_down(eacc, off, 64);
        int lane = t & 63, wid = t >> 6;
        if (lane == 0) wsum[wid] = eacc;
        __syncthreads();
        if (t == 0)
            partials[b] = (wsum[0] + wsum[1]) + (wsum[2] + wsum[3]);
    }
    gbar(bar, bar + 48);

    // -------- Phase 4: out[v] = logits[v] - log(sum partials) ---------------
    if (b >= (VOCAB + 255) / 256) return;   // 197 blocks cover the output
    {
        float acc = 0.f;
        for (int i = t; i < GRID; i += 256) acc += partials[i];
        for (int off = 32; off > 0; off >>= 1) acc += __shfl_down(acc, off, 64);
        int lane = t & 63, wid = t >> 6;
        if (lane == 0) wsum[wid] = acc;
        __syncthreads();
        if (t == 0)
            lzs = logf((wsum[0] + wsum[1]) + (wsum[2] + wsum[3]));
        __syncthreads();
        int v = b * 256 + t;
        if (v < VOCAB) out[v] = logits[v] - lzs;
    }
}

extern "C" void kernel_launch(void* const* d_in, const int* in_sizes, int n_in,
                              void* d_out, int out_size, void* d_ws, size_t ws_size,
                              hipStream_t stream) {
    const float* X    = (const float*)d_in[0];   // [CTX, VOCAB]
    const int*   lenp = (const int*)d_in[1];     // scalar 200
    const float* Wq   = (const float*)d_in[2];   // [EMB, VOCAB]
    const float* bq   = (const float*)d_in[3];   // [EMB]
    const float* Ww   = (const float*)d_in[4];   // [VOCAB, EMB]
    const float* bw   = (const float*)d_in[5];   // [VOCAB]
    float* out = (float*)d_out;                  // [VOCAB]

    // Workspace (floats):
    //   [0, 4096)        hpart [32][128]
    //   [4096, 4884)     partials [788]
    //   [5120, 5184)     barrier ints (ready, c1, c2, c3 in separate lines)
    //   [8192, 8192+4V)  spart [4][VOCAB] (slab 0 re-used as logits in P3/P4)
    float* ws       = (float*)d_ws;
    float* hpart    = ws;
    float* partials = ws + 4096;
    int*   bar      = (int*)(ws + 5120);
    float* spart    = ws + 8192;

    k_fused<<<GRID, 256, 0, stream>>>(X, lenp, Wq, bq, Ww, bw, out,
                                      spart, hpart, partials, bar);
}

// Round 7
// 166.552 us; speedup vs baseline: 2.4222x; 2.4222x over previous
//
#include <hip/hip_runtime.h>
#include <math.h>

#define VOCAB 50257
#define EMB   128
#define CTX   200
#define CSLABS 197                 // column slabs of 256
#define RSLABS 8                   // row slabs of 25
#define ROWS   25
#define HCHUNKS 32
#define K3_BLOCKS 788
#define NT ((VOCAB + 15) / 16)     // 3142 Ww row-tiles of 16

// ---------------- K1: spart[r][v] = sum of 25 rows of X ---------------------
// grid (197, 8) x 256. 25 outstanding scalar loads per thread (one burst).
// Also zeroes the K3 completion counter (stream order makes it visible).
__global__ __launch_bounds__(256)
void k1(const float* __restrict__ X, float* __restrict__ spart,
        int* __restrict__ done) {
    if (blockIdx.x == 0 && blockIdx.y == 0 && threadIdx.x == 0)
        __hip_atomic_store(done, 0, __ATOMIC_RELAXED, __HIP_MEMORY_SCOPE_AGENT);
    int v = blockIdx.x * 256 + threadIdx.x;
    if (v >= VOCAB) return;
    const float* p = X + (size_t)(blockIdx.y * ROWS) * VOCAB + v;
    float a[ROWS];
#pragma unroll
    for (int j = 0; j < ROWS; ++j) a[j] = p[(size_t)j * VOCAB];
    float s0 = ((a[0] + a[1]) + (a[2] + a[3])) + a[4];
    float s1 = ((a[5] + a[6]) + (a[7] + a[8])) + a[9];
    float s2 = ((a[10] + a[11]) + (a[12] + a[13])) + a[14];
    float s3 = ((a[15] + a[16]) + (a[17] + a[18])) + a[19];
    float s4 = ((a[20] + a[21]) + (a[22] + a[23])) + a[24];
    spart[(size_t)blockIdx.y * VOCAB + v] = ((s0 + s1) + (s2 + s3)) + s4;
}

// ---------------- K2: hpart[chunk][e] = partial dot(s, Wq[e,:]) -------------
// grid (32, 32) x 256: block = (chunk, e-group of 4). One spart read serves
// 4 Wq rows (spart L2 re-reads /4 vs R3). Plain stores, no atomics.
__global__ __launch_bounds__(256)
void k2(const float* __restrict__ Wq, const float* __restrict__ spart,
        float* __restrict__ hpart) {
    const int chunk = blockIdx.x;
    const int e0    = blockIdx.y * 4;
    const int t     = threadIdx.x;
    const float* r0 = Wq + (size_t)(e0 + 0) * VOCAB;
    const float* r1 = Wq + (size_t)(e0 + 1) * VOCAB;
    const float* r2 = Wq + (size_t)(e0 + 2) * VOCAB;
    const float* r3 = Wq + (size_t)(e0 + 3) * VOCAB;
    float a0 = 0.f, a1 = 0.f, a2 = 0.f, a3 = 0.f;
    for (int v = chunk * 256 + t; v < VOCAB; v += HCHUNKS * 256) {
        float sv = 0.f;
#pragma unroll
        for (int s = 0; s < RSLABS; ++s) sv += spart[(size_t)s * VOCAB + v];
        a0 += sv * r0[v];
        a1 += sv * r1[v];
        a2 += sv * r2[v];
        a3 += sv * r3[v];
    }
    for (int off = 32; off > 0; off >>= 1) {
        a0 += __shfl_down(a0, off, 64);
        a1 += __shfl_down(a1, off, 64);
        a2 += __shfl_down(a2, off, 64);
        a3 += __shfl_down(a3, off, 64);
    }
    __shared__ float wsum[4][4];
    int lane = t & 63, wid = t >> 6;
    if (lane == 0) { wsum[wid][0] = a0; wsum[wid][1] = a1;
                     wsum[wid][2] = a2; wsum[wid][3] = a3; }
    __syncthreads();
    if (t < 4)
        hpart[chunk * EMB + e0 + t] =
            (wsum[0][t] + wsum[1][t]) + (wsum[2][t] + wsum[3][t]);
}

// ---------------- K3: logits + exp partials + last-block finalize -----------
// grid 788 x 256. Per block: build h from hpart (L2), ~4 Ww tiles of 16 rows
// (16 lanes/row, two float4 loads/lane), store exp partial, then ONE agent
// atomicAdd on done. The block seeing old==787 computes logZ and writes out.
__global__ __launch_bounds__(256)
void k3(const float* __restrict__ Ww, const float* __restrict__ bw,
        const float* __restrict__ hpart, const float* __restrict__ bq,
        const int* __restrict__ lenp,
        float* __restrict__ logits, float* __restrict__ partials,
        int* __restrict__ done, float* __restrict__ out) {
    __shared__ float h[EMB];
    __shared__ float wsum[4];
    __shared__ int lastFlag;
    __shared__ float lzs;
    const int t = threadIdx.x, b = blockIdx.x;

    if (t < EMB) {
        float hr = 0.f;
#pragma unroll
        for (int c = 0; c < HCHUNKS; ++c) hr += hpart[c * EMB + t];
        h[t] = (hr + (float)CTX * bq[t]) / (float)lenp[0];
    }
    __syncthreads();

    int group = t >> 4;                 // row within 16-row tile
    int c     = t & 15;                 // lane within row
    float eacc = 0.f;
    for (int tile = b; tile < NT; tile += K3_BLOCKS) {
        int v = tile * 16 + group;
        float acc = 0.f;
        if (v < VOCAB) {
            const float4* row = (const float4*)(Ww + (size_t)v * EMB);
            float4 w0 = row[c * 2];
            float4 w1 = row[c * 2 + 1];
            const float* hp = h + c * 8;
            acc = w0.x * hp[0] + w0.y * hp[1] + w0.z * hp[2] + w0.w * hp[3]
                + w1.x * hp[4] + w1.y * hp[5] + w1.z * hp[6] + w1.w * hp[7];
        }
        acc += __shfl_xor(acc, 1, 64);
        acc += __shfl_xor(acc, 2, 64);
        acc += __shfl_xor(acc, 4, 64);
        acc += __shfl_xor(acc, 8, 64);
        if (v < VOCAB && c == 0) {
            float lg = acc + bw[v];
            logits[v] = lg;
            eacc += expf(lg);
        }
    }
    for (int off = 32; off > 0; off >>= 1) eacc += __shfl_down(eacc, off, 64);
    int lane = t & 63, wid = t >> 6;
    if (lane == 0) wsum[wid] = eacc;
    __syncthreads();
    if (t == 0) {
        partials[b] = (wsum[0] + wsum[1]) + (wsum[2] + wsum[3]);
        __threadfence();               // release logits + partials
        int old = __hip_atomic_fetch_add(done, 1, __ATOMIC_ACQ_REL,
                                         __HIP_MEMORY_SCOPE_AGENT);
        lastFlag = (old == K3_BLOCKS - 1);
    }
    __syncthreads();
    if (!lastFlag) return;

    // ---- last block only: logZ + finalize all of out -----------------------
    __threadfence();                   // acquire side
    float acc = 0.f;
    for (int i = t; i < K3_BLOCKS; i += 256) acc += partials[i];
    for (int off = 32; off > 0; off >>= 1) acc += __shfl_down(acc, off, 64);
    if (lane == 0) wsum[wid] = acc;
    __syncthreads();
    if (t == 0)
        lzs = logf((wsum[0] + wsum[1]) + (wsum[2] + wsum[3]));
    __syncthreads();
    float lz = lzs;
#pragma unroll 4
    for (int v = t; v < VOCAB; v += 256) out[v] = logits[v] - lz;
}

extern "C" void kernel_launch(void* const* d_in, const int* in_sizes, int n_in,
                              void* d_out, int out_size, void* d_ws, size_t ws_size,
                              hipStream_t stream) {
    const float* X    = (const float*)d_in[0];   // [CTX, VOCAB]
    const int*   lenp = (const int*)d_in[1];     // scalar 200
    const float* Wq   = (const float*)d_in[2];   // [EMB, VOCAB]
    const float* bq   = (const float*)d_in[3];   // [EMB]
    const float* Ww   = (const float*)d_in[4];   // [VOCAB, EMB]
    const float* bw   = (const float*)d_in[5];   // [VOCAB]
    float* out = (float*)d_out;                  // [VOCAB]

    // Workspace (floats):
    //   [0, 4096)        hpart [32][128]
    //   [4096, 4884)     partials [788]
    //   [5120]           done counter (int), zeroed by K1 each launch
    //   [8192, 8192+8V)  spart [8][VOCAB]; slab 0 re-used as logits in K3
    //   (safe: K2 is the last spart reader and precedes K3 in stream order)
    float* ws       = (float*)d_ws;
    float* hpart    = ws;
    float* partials = ws + 4096;
    int*   done     = (int*)(ws + 5120);
    float* spart    = ws + 8192;
    float* logits   = spart;

    dim3 g1(CSLABS, RSLABS);
    k1<<<g1, 256, 0, stream>>>(X, spart, done);

    dim3 g2(HCHUNKS, EMB / 4);
    k2<<<g2, 256, 0, stream>>>(Wq, spart, hpart);

    k3<<<K3_BLOCKS, 256, 0, stream>>>(Ww, bw, hpart, bq, lenp,
                                      logits, partials, done, out);
}

// Round 8
// 133.865 us; speedup vs baseline: 3.0136x; 1.2442x over previous
//
#include <hip/hip_runtime.h>
#include <math.h>

#define VOCAB 50257
#define EMB   128
#define CTX   200
#define CSLABS 197                 // column slabs of 256
#define RSLABS 8                   // row slabs of 25
#define ROWS   25
#define HCHUNKS 32
#define K3_BLOCKS 788
#define NT ((VOCAB + 15) / 16)     // 3142 Ww row-tiles of 16

// ---------------- K1: spart[r][v] = sum of 25 rows of X ---------------------
// grid (197, 8) x 256. 25 outstanding scalar loads per thread (one burst),
// 1576 blocks (~24 waves/CU). Plain stores, no atomics.
__global__ __launch_bounds__(256)
void k1(const float* __restrict__ X, float* __restrict__ spart) {
    int v = blockIdx.x * 256 + threadIdx.x;
    if (v >= VOCAB) return;
    const float* p = X + (size_t)(blockIdx.y * ROWS) * VOCAB + v;
    float a[ROWS];
#pragma unroll
    for (int j = 0; j < ROWS; ++j) a[j] = p[(size_t)j * VOCAB];
    float s0 = ((a[0] + a[1]) + (a[2] + a[3])) + a[4];
    float s1 = ((a[5] + a[6]) + (a[7] + a[8])) + a[9];
    float s2 = ((a[10] + a[11]) + (a[12] + a[13])) + a[14];
    float s3 = ((a[15] + a[16]) + (a[17] + a[18])) + a[19];
    float s4 = ((a[20] + a[21]) + (a[22] + a[23])) + a[24];
    spart[(size_t)blockIdx.y * VOCAB + v] = ((s0 + s1) + (s2 + s3)) + s4;
}

// ---------------- K2: hpart[chunk][e0..e0+3] = partial dot(s, Wq[e,:]) ------
// grid (32, 32) x 256: block = (chunk, e-group of 4). One spart read serves
// 4 Wq rows. Plain stores, no atomics.
__global__ __launch_bounds__(256)
void k2(const float* __restrict__ Wq, const float* __restrict__ spart,
        float* __restrict__ hpart) {
    const int chunk = blockIdx.x;
    const int e0    = blockIdx.y * 4;
    const int t     = threadIdx.x;
    const float* r0 = Wq + (size_t)(e0 + 0) * VOCAB;
    const float* r1 = Wq + (size_t)(e0 + 1) * VOCAB;
    const float* r2 = Wq + (size_t)(e0 + 2) * VOCAB;
    const float* r3 = Wq + (size_t)(e0 + 3) * VOCAB;
    float a0 = 0.f, a1 = 0.f, a2 = 0.f, a3 = 0.f;
    for (int v = chunk * 256 + t; v < VOCAB; v += HCHUNKS * 256) {
        float sv = 0.f;
#pragma unroll
        for (int s = 0; s < RSLABS; ++s) sv += spart[(size_t)s * VOCAB + v];
        a0 += sv * r0[v];
        a1 += sv * r1[v];
        a2 += sv * r2[v];
        a3 += sv * r3[v];
    }
    for (int off = 32; off > 0; off >>= 1) {
        a0 += __shfl_down(a0, off, 64);
        a1 += __shfl_down(a1, off, 64);
        a2 += __shfl_down(a2, off, 64);
        a3 += __shfl_down(a3, off, 64);
    }
    __shared__ float wsum[4][4];
    int lane = t & 63, wid = t >> 6;
    if (lane == 0) { wsum[wid][0] = a0; wsum[wid][1] = a1;
                     wsum[wid][2] = a2; wsum[wid][3] = a3; }
    __syncthreads();
    if (t < 4)
        hpart[chunk * EMB + e0 + t] =
            (wsum[0][t] + wsum[1][t]) + (wsum[2][t] + wsum[3][t]);
}

// ---------------- K3: logits + per-block exp partial (NO atomics) -----------
// grid 788 x 256. Build h from hpart (L2-hot), then ~4 Ww tiles of 16 rows:
// 16 lanes/row, two float4 loads/lane over the contiguous 512B row.
__global__ __launch_bounds__(256)
void k3(const float* __restrict__ Ww, const float* __restrict__ bw,
        const float* __restrict__ hpart, const float* __restrict__ bq,
        const int* __restrict__ lenp,
        float* __restrict__ logits, float* __restrict__ partials) {
    __shared__ float h[EMB];
    __shared__ float wsum[4];
    const int t = threadIdx.x, b = blockIdx.x;

    if (t < EMB) {
        float hr = 0.f;
#pragma unroll
        for (int c = 0; c < HCHUNKS; ++c) hr += hpart[c * EMB + t];
        h[t] = (hr + (float)CTX * bq[t]) / (float)lenp[0];
    }
    __syncthreads();

    int group = t >> 4;                 // row within 16-row tile
    int c     = t & 15;                 // lane within row
    float eacc = 0.f;
    for (int tile = b; tile < NT; tile += K3_BLOCKS) {
        int v = tile * 16 + group;
        float acc = 0.f;
        if (v < VOCAB) {
            const float4* row = (const float4*)(Ww + (size_t)v * EMB);
            float4 w0 = row[c * 2];
            float4 w1 = row[c * 2 + 1];
            const float* hp = h + c * 8;
            acc = w0.x * hp[0] + w0.y * hp[1] + w0.z * hp[2] + w0.w * hp[3]
                + w1.x * hp[4] + w1.y * hp[5] + w1.z * hp[6] + w1.w * hp[7];
        }
        acc += __shfl_xor(acc, 1, 64);
        acc += __shfl_xor(acc, 2, 64);
        acc += __shfl_xor(acc, 4, 64);
        acc += __shfl_xor(acc, 8, 64);
        if (v < VOCAB && c == 0) {
            float lg = acc + bw[v];
            logits[v] = lg;
            eacc += expf(lg);
        }
    }
    for (int off = 32; off > 0; off >>= 1) eacc += __shfl_down(eacc, off, 64);
    int lane = t & 63, wid = t >> 6;
    if (lane == 0) wsum[wid] = eacc;
    __syncthreads();
    if (t == 0)
        partials[b] = (wsum[0] + wsum[1]) + (wsum[2] + wsum[3]);
}

// ---------------- K4: out[v] = logits[v] - log(sum partials) ----------------
// 197 blocks each redundantly reduce the 788 partials (3 KB, L2-hot).
__global__ __launch_bounds__(256)
void k4(const float* __restrict__ logits, const float* __restrict__ partials,
        float* __restrict__ out) {
    __shared__ float wsum[4];
    __shared__ float lz;
    float acc = 0.f;
    for (int i = threadIdx.x; i < K3_BLOCKS; i += 256) acc += partials[i];
    for (int off = 32; off > 0; off >>= 1) acc += __shfl_down(acc, off, 64);
    int lane = threadIdx.x & 63, wid = threadIdx.x >> 6;
    if (lane == 0) wsum[wid] = acc;
    __syncthreads();
    if (threadIdx.x == 0)
        lz = logf((wsum[0] + wsum[1]) + (wsum[2] + wsum[3]));
    __syncthreads();
    int v = blockIdx.x * 256 + threadIdx.x;
    if (v < VOCAB) out[v] = logits[v] - lz;
}

extern "C" void kernel_launch(void* const* d_in, const int* in_sizes, int n_in,
                              void* d_out, int out_size, void* d_ws, size_t ws_size,
                              hipStream_t stream) {
    const float* X    = (const float*)d_in[0];   // [CTX, VOCAB]
    const int*   lenp = (const int*)d_in[1];     // scalar 200
    const float* Wq   = (const float*)d_in[2];   // [EMB, VOCAB]
    const float* bq   = (const float*)d_in[3];   // [EMB]
    const float* Ww   = (const float*)d_in[4];   // [VOCAB, EMB]
    const float* bw   = (const float*)d_in[5];   // [VOCAB]
    float* out = (float*)d_out;                  // [VOCAB]

    // Workspace (floats) — all plain stores, nothing needs zeroing:
    //   [0, 4096)        hpart [32][128]
    //   [4096, 4884)     partials [788]
    //   [8192, 8192+8V)  spart [8][VOCAB]; slab 0 re-used as logits by K3
    //   (safe: K2 is the last spart reader and precedes K3 in stream order)
    float* ws       = (float*)d_ws;
    float* hpart    = ws;
    float* partials = ws + 4096;
    float* spart    = ws + 8192;
    float* logits   = spart;

    dim3 g1(CSLABS, RSLABS);
    k1<<<g1, 256, 0, stream>>>(X, spart);

    dim3 g2(HCHUNKS, EMB / 4);
    k2<<<g2, 256, 0, stream>>>(Wq, spart, hpart);

    k3<<<K3_BLOCKS, 256, 0, stream>>>(Ww, bw, hpart, bq, lenp, logits, partials);

    k4<<<(VOCAB + 255) / 256, 256, 0, stream>>>(logits, partials, out);
}